// Round 3
// baseline (253.161 us; speedup 1.0000x reference)
//
#include <hip/hip_runtime.h>
#include <hip/hip_bf16.h>
#include <math.h>

#define B_SZ 8
#define SEQ 2048
#define DIM 512

typedef __attribute__((ext_vector_type(8))) short bf16x8;
typedef __attribute__((ext_vector_type(8))) unsigned short u16x8;
typedef __attribute__((ext_vector_type(4))) float f32x4;

#define GLOBAL_AS __attribute__((address_space(1)))
#define LDS_AS __attribute__((address_space(3)))

__device__ __forceinline__ unsigned short f2bf(float f) {
    unsigned int u = __builtin_bit_cast(unsigned int, f);
    u += 0x7fffu + ((u >> 16) & 1u);   // RNE
    return (unsigned short)(u >> 16);
}

__device__ __forceinline__ void load_lds16(const void* g, void* l) {
    __builtin_amdgcn_global_load_lds((const GLOBAL_AS unsigned int*)g,
                                     (LDS_AS unsigned int*)l, 16, 0, 0);
}

// ---- fp32 -> bf16, 8 elems/thread; grid.y selects Q or K ----
__global__ __launch_bounds__(256)
void convert_kernel(const float* __restrict__ Qs, const float* __restrict__ Ks,
                    unsigned short* __restrict__ Qd, unsigned short* __restrict__ Kd) {
    const float* src = blockIdx.y ? Qs : Ks;
    unsigned short* dst = blockIdx.y ? Qd : Kd;
    int i = blockIdx.x * 256 + threadIdx.x;
    const float4* s = (const float4*)src;
    float4 a = s[2 * i];
    float4 b = s[2 * i + 1];
    u16x8 o;
    o[0] = f2bf(a.x); o[1] = f2bf(a.y); o[2] = f2bf(a.z); o[3] = f2bf(a.w);
    o[4] = f2bf(b.x); o[5] = f2bf(b.y); o[6] = f2bf(b.z); o[7] = f2bf(b.w);
    ((u16x8*)dst)[i] = o;
}

// ---- P = exp((Q K^T)/sqrt(SEQ)), causal-masked, unnormalized; partial row
// sums to ws. Upper-triangle tiles write final zeros. 128x128 tile, BK=32. ----
#define BM 128
#define BK 32
__global__ __launch_bounds__(256)
void logits_exp(const unsigned short* __restrict__ Qb, const unsigned short* __restrict__ Kb,
                float* __restrict__ out, float* __restrict__ partials) {
    const int tk = blockIdx.x, tq = blockIdx.y, b = blockIdx.z;
    const int t = threadIdx.x;
    float* outb = out + (size_t)b * SEQ * SEQ;

    if (tk > tq) {   // strictly above diagonal: final zeros
        float4 z = {0.f, 0.f, 0.f, 0.f};
        float4* o = (float4*)(outb + (size_t)(tq * BM) * SEQ + tk * BM);
        const int c4 = t & 31;            // 32 float4 per row
        const int r0 = t >> 5;            // 8 rows per sweep
#pragma unroll
        for (int r = 0; r < BM; r += 8)
            o[(size_t)(r + r0) * (SEQ / 4) + c4] = z;
        return;
    }

    __shared__ __align__(16) unsigned short a_lds[BM * BK];  // 8 KiB
    __shared__ __align__(16) unsigned short b_lds[BM * BK];  // 8 KiB

    const int wave = t >> 6;
    const int lane = t & 63;
    const int l16 = lane & 15;
    const int quad = lane >> 4;
    const int wm = wave >> 1;      // 2x2 wave grid, each wave 64x64
    const int wn = wave & 1;

    const unsigned short* Qrow = Qb + ((size_t)b * SEQ + (size_t)tq * BM) * DIM;
    const unsigned short* Krow = Kb + ((size_t)b * SEQ + (size_t)tk * BM) * DIM;

    const int sr = lane >> 2;      // 0..15 row-within-instr
    const int kg = lane & 3;       // 0..3  k-group (8 bf16 each)

    f32x4 acc[4][4];
#pragma unroll
    for (int i = 0; i < 4; i++)
#pragma unroll
        for (int j = 0; j < 4; j++) acc[i][j] = (f32x4){0.f, 0.f, 0.f, 0.f};

    for (int k0 = 0; k0 < DIM; k0 += BK) {
#pragma unroll
        for (int j = wave; j < 8; j += 4) {
            int row = j * 16 + sr;
            load_lds16(Qrow + (size_t)row * DIM + k0 + kg * 8, &a_lds[(j * 16) * BK]);
            load_lds16(Krow + (size_t)row * DIM + k0 + kg * 8, &b_lds[(j * 16) * BK]);
        }
        __syncthreads();

        bf16x8 af[4], bf[4];
#pragma unroll
        for (int mi = 0; mi < 4; mi++)
            af[mi] = *(const bf16x8*)&a_lds[(wm * 64 + mi * 16 + l16) * BK + quad * 8];
#pragma unroll
        for (int ni = 0; ni < 4; ni++)
            bf[ni] = *(const bf16x8*)&b_lds[(wn * 64 + ni * 16 + l16) * BK + quad * 8];
#pragma unroll
        for (int mi = 0; mi < 4; mi++)
#pragma unroll
            for (int ni = 0; ni < 4; ni++)
                acc[mi][ni] = __builtin_amdgcn_mfma_f32_16x16x32_bf16(af[mi], bf[ni], acc[mi][ni], 0, 0, 0);
        __syncthreads();
    }

    const float scale = 0.02209708691207961f;  // 1/sqrt(2048)
    const bool diag = (tk == tq);
#pragma unroll
    for (int mi = 0; mi < 4; mi++) {
        const int rowb = tq * BM + wm * 64 + mi * 16 + quad * 4;
#pragma unroll
        for (int r = 0; r < 4; r++) {
            const int row = rowb + r;
            float psum = 0.f;
#pragma unroll
            for (int ni = 0; ni < 4; ni++) {
                const int col = tk * BM + wn * 64 + ni * 16 + l16;
                float e = __expf(acc[mi][ni][r] * scale);
                e = (!diag || col <= row) ? e : 0.f;
                psum += e;
                outb[(size_t)row * SEQ + col] = e;
            }
            // reduce over the 16 lanes sharing this row (l16 group)
            psum += __shfl_xor(psum, 1);
            psum += __shfl_xor(psum, 2);
            psum += __shfl_xor(psum, 4);
            psum += __shfl_xor(psum, 8);
            if (l16 == 0)
                partials[((size_t)b * SEQ + row) * 32 + tk * 2 + wn] = psum;
        }
    }
}

// ---- per-row rescale: P /= rowsum, lower-triangle tiles only ----
__global__ __launch_bounds__(256)
void rescale_kernel(float* __restrict__ out, const float* __restrict__ partials) {
    const int q = blockIdx.x & (SEQ - 1);
    const int b = blockIdx.x >> 11;
    const int t = threadIdx.x;
    const int lane = t & 63;
    const int tqt = q >> 7;                 // tile row
    const int nslots = (tqt + 1) * 2;

    float v = 0.f;
    if (lane < nslots) v = partials[((size_t)(b * SEQ + q)) * 32 + lane];
    v += __shfl_xor(v, 1);
    v += __shfl_xor(v, 2);
    v += __shfl_xor(v, 4);
    v += __shfl_xor(v, 8);
    v += __shfl_xor(v, 16);
    const float inv = 1.0f / __shfl(v, 0);

    float4* row = (float4*)(out + ((size_t)b * SEQ + q) * SEQ);
    const int n4 = (tqt + 1) * 32;          // float4s through the diagonal tile
    for (int i = t; i < n4; i += 256) {
        float4 e = row[i];
        e.x *= inv; e.y *= inv; e.z *= inv; e.w *= inv;
        row[i] = e;
    }
}

extern "C" void kernel_launch(void* const* d_in, const int* in_sizes, int n_in,
                              void* d_out, int out_size, void* d_ws, size_t ws_size,
                              hipStream_t stream) {
    // setup_inputs order: {"K": ..., "Q": ...}
    const float* Kp = (const float*)d_in[0];
    const float* Qp = (const float*)d_in[1];
    float* out = (float*)d_out;

    const size_t nElem = (size_t)B_SZ * SEQ * DIM;
    unsigned short* Qbf = (unsigned short*)d_ws;
    unsigned short* Kbf = Qbf + nElem;
    float* partials = (float*)(Kbf + nElem);          // [B*SEQ][32]

    convert_kernel<<<dim3((unsigned)(nElem / 2048), 2), dim3(256), 0, stream>>>(Qp, Kp, Qbf, Kbf);
    logits_exp<<<dim3(SEQ / BM, SEQ / BM, B_SZ), dim3(256), 0, stream>>>(Qbf, Kbf, out, partials);
    rescale_kernel<<<dim3(B_SZ * SEQ), dim3(256), 0, stream>>>(out, partials);
}

// Round 5
// 250.586 us; speedup vs baseline: 1.0103x; 1.0103x over previous
//
#include <hip/hip_runtime.h>
#include <hip/hip_bf16.h>
#include <math.h>

#define B_SZ 8
#define SEQ 2048
#define DIM 512
#define NT (SEQ / 128)              // 16 tile rows
#define NTRI (NT * (NT + 1) / 2)    // 136 lower-triangle tiles

typedef __attribute__((ext_vector_type(8))) short bf16x8;
typedef __attribute__((ext_vector_type(8))) unsigned short u16x8;
typedef __attribute__((ext_vector_type(4))) float f32x4;

#define GLOBAL_AS __attribute__((address_space(1)))
#define LDS_AS __attribute__((address_space(3)))

__device__ __forceinline__ unsigned short f2bf(float f) {
    unsigned int u = __builtin_bit_cast(unsigned int, f);
    u += 0x7fffu + ((u >> 16) & 1u);   // RNE
    return (unsigned short)(u >> 16);
}

__device__ __forceinline__ void load_lds16(const void* g, void* l) {
    __builtin_amdgcn_global_load_lds((const GLOBAL_AS unsigned int*)g,
                                     (LDS_AS unsigned int*)l, 16, 0, 0);
}

// ---- fp32 -> bf16, 64 elems/thread; grid (512, 2) ----
__global__ __launch_bounds__(256)
void convert_kernel(const float* __restrict__ Qs, const float* __restrict__ Ks,
                    unsigned short* __restrict__ Qd, unsigned short* __restrict__ Kd) {
    const float* src = blockIdx.y ? Qs : Ks;
    unsigned short* dst = blockIdx.y ? Qd : Kd;
    const int base = blockIdx.x * (256 * 8) + threadIdx.x;   // u16x8 units
    const float4* s = (const float4*)src;
#pragma unroll
    for (int j = 0; j < 8; j++) {
        int i = base + j * 256;
        float4 a = s[2 * i];
        float4 b = s[2 * i + 1];
        u16x8 o;
        o[0] = f2bf(a.x); o[1] = f2bf(a.y); o[2] = f2bf(a.z); o[3] = f2bf(a.w);
        o[4] = f2bf(b.x); o[5] = f2bf(b.y); o[6] = f2bf(b.z); o[7] = f2bf(b.w);
        ((u16x8*)dst)[i] = o;
    }
}

// ---- P = exp((Q K^T)/sqrt(SEQ)) unnormalized, lower-triangle tiles only.
// Triangular linear grid: 136 tiles x 8 batches. 128x128 tile, BK=32. ----
#define BM 128
#define BK 32
__global__ __launch_bounds__(256)
void logits_exp(const unsigned short* __restrict__ Qb, const unsigned short* __restrict__ Kb,
                float* __restrict__ out, float* __restrict__ partials) {
    const int tid = blockIdx.x;          // 0..135
    const int b = blockIdx.y;
    // decode lower-triangle (tq, tk) from linear index
    int tq = (int)((sqrtf(8.f * (float)tid + 1.f) - 1.f) * 0.5f);
    while ((tq + 1) * (tq + 2) / 2 <= tid) tq++;
    while (tq * (tq + 1) / 2 > tid) tq--;
    const int tk = tid - tq * (tq + 1) / 2;   // 0..tq  (tq <= 15)

    __shared__ __align__(16) unsigned short a_lds[BM * BK];  // 8 KiB
    __shared__ __align__(16) unsigned short b_lds[BM * BK];  // 8 KiB

    const int t = threadIdx.x;
    const int wave = t >> 6;
    const int lane = t & 63;
    const int l16 = lane & 15;
    const int quad = lane >> 4;
    const int wm = wave >> 1;      // 2x2 wave grid, each wave 64x64
    const int wn = wave & 1;

    const unsigned short* Qrow = Qb + ((size_t)b * SEQ + (size_t)tq * BM) * DIM;
    const unsigned short* Krow = Kb + ((size_t)b * SEQ + (size_t)tk * BM) * DIM;

    const int sr = lane >> 2;      // 0..15 row-within-instr
    const int kg = lane & 3;       // 0..3  k-group (8 bf16 each)

    f32x4 acc[4][4];
#pragma unroll
    for (int i = 0; i < 4; i++)
#pragma unroll
        for (int j = 0; j < 4; j++) acc[i][j] = (f32x4){0.f, 0.f, 0.f, 0.f};

    for (int k0 = 0; k0 < DIM; k0 += BK) {
#pragma unroll
        for (int j = wave; j < 8; j += 4) {
            int row = j * 16 + sr;
            load_lds16(Qrow + (size_t)row * DIM + k0 + kg * 8, &a_lds[(j * 16) * BK]);
            load_lds16(Krow + (size_t)row * DIM + k0 + kg * 8, &b_lds[(j * 16) * BK]);
        }
        __syncthreads();

        bf16x8 af[4], bf[4];
#pragma unroll
        for (int mi = 0; mi < 4; mi++)
            af[mi] = *(const bf16x8*)&a_lds[(wm * 64 + mi * 16 + l16) * BK + quad * 8];
#pragma unroll
        for (int ni = 0; ni < 4; ni++)
            bf[ni] = *(const bf16x8*)&b_lds[(wn * 64 + ni * 16 + l16) * BK + quad * 8];
#pragma unroll
        for (int mi = 0; mi < 4; mi++)
#pragma unroll
            for (int ni = 0; ni < 4; ni++)
                acc[mi][ni] = __builtin_amdgcn_mfma_f32_16x16x32_bf16(af[mi], bf[ni], acc[mi][ni], 0, 0, 0);
        __syncthreads();
    }

    const float scale = 0.02209708691207961f;  // 1/sqrt(2048)
    const bool diag = (tk == tq);
    float* outb = out + (size_t)b * SEQ * SEQ;
#pragma unroll
    for (int mi = 0; mi < 4; mi++) {
        const int rowb = tq * BM + wm * 64 + mi * 16 + quad * 4;
#pragma unroll
        for (int r = 0; r < 4; r++) {
            const int row = rowb + r;
            float psum = 0.f;
#pragma unroll
            for (int ni = 0; ni < 4; ni++) {
                const int col = tk * BM + wn * 64 + ni * 16 + l16;
                float e = __expf(acc[mi][ni][r] * scale);
                e = (!diag || col <= row) ? e : 0.f;
                psum += e;
                outb[(size_t)row * SEQ + col] = e;
            }
            psum += __shfl_xor(psum, 1);
            psum += __shfl_xor(psum, 2);
            psum += __shfl_xor(psum, 4);
            psum += __shfl_xor(psum, 8);
            if (l16 == 0)
                partials[((size_t)b * SEQ + row) * 32 + tk * 2 + wn] = psum;
        }
    }
}

// ---- per-row rescale + upper-triangle zero fill: 8 rows/block ----
__global__ __launch_bounds__(256)
void rescale_kernel(float* __restrict__ out, const float* __restrict__ partials) {
    const int rowbase = blockIdx.x * 8;          // global row in [0, B*SEQ)
    const int wave = threadIdx.x >> 6;
    const int lane = threadIdx.x & 63;
#pragma unroll
    for (int rr = 0; rr < 2; rr++) {
        const int grow = rowbase + wave * 2 + rr;
        const int q = grow & (SEQ - 1);
        const int tqt = q >> 7;
        const int nslots = (tqt + 1) * 2;        // <= 32
        float v = (lane < nslots) ? partials[(size_t)grow * 32 + lane] : 0.f;
        v += __shfl_xor(v, 1);
        v += __shfl_xor(v, 2);
        v += __shfl_xor(v, 4);
        v += __shfl_xor(v, 8);
        v += __shfl_xor(v, 16);
        v += __shfl_xor(v, 32);
        const float inv = 1.0f / v;
        const int n4 = (tqt + 1) * 32;           // valid float4 count (thru diag tile)
        float4* row = (float4*)(out + (size_t)grow * SEQ);
#pragma unroll
        for (int j = 0; j < 8; j++) {
            const int i = lane + j * 64;
            if (i < n4) {
                float4 e = row[i];
                e.x *= inv; e.y *= inv; e.z *= inv; e.w *= inv;
                row[i] = e;
            } else {
                row[i] = (float4){0.f, 0.f, 0.f, 0.f};
            }
        }
    }
}

extern "C" void kernel_launch(void* const* d_in, const int* in_sizes, int n_in,
                              void* d_out, int out_size, void* d_ws, size_t ws_size,
                              hipStream_t stream) {
    // setup_inputs order: {"K": ..., "Q": ...}
    const float* Kp = (const float*)d_in[0];
    const float* Qp = (const float*)d_in[1];
    float* out = (float*)d_out;

    const size_t nElem = (size_t)B_SZ * SEQ * DIM;
    unsigned short* Qbf = (unsigned short*)d_ws;
    unsigned short* Kbf = Qbf + nElem;
    float* partials = (float*)(Kbf + nElem);          // [B*SEQ][32]

    convert_kernel<<<dim3(512, 2), dim3(256), 0, stream>>>(Qp, Kp, Qbf, Kbf);
    logits_exp<<<dim3(NTRI, B_SZ), dim3(256), 0, stream>>>(Qbf, Kbf, out, partials);
    rescale_kernel<<<dim3(B_SZ * SEQ / 8), dim3(256), 0, stream>>>(out, partials);
}

// Round 6
// 248.831 us; speedup vs baseline: 1.0174x; 1.0071x over previous
//
#include <hip/hip_runtime.h>
#include <hip/hip_bf16.h>
#include <math.h>

#define B_SZ 8
#define SEQ 2048
#define DIM 512
#define NT (SEQ / 128)              // 16 tile rows
#define NTRI (NT * (NT + 1) / 2)    // 136 lower-triangle tiles

typedef __attribute__((ext_vector_type(8))) short bf16x8;
typedef __attribute__((ext_vector_type(8))) unsigned short u16x8;
typedef __attribute__((ext_vector_type(4))) float f32x4;

#define GLOBAL_AS __attribute__((address_space(1)))
#define LDS_AS __attribute__((address_space(3)))

__device__ __forceinline__ unsigned short f2bf(float f) {
    unsigned int u = __builtin_bit_cast(unsigned int, f);
    u += 0x7fffu + ((u >> 16) & 1u);   // RNE
    return (unsigned short)(u >> 16);
}

__device__ __forceinline__ void load_lds16(const void* g, void* l) {
    __builtin_amdgcn_global_load_lds((const GLOBAL_AS unsigned int*)g,
                                     (LDS_AS unsigned int*)l, 16, 0, 0);
}

// ---- fp32 -> bf16, 64 elems/thread; grid (512, 2) ----
__global__ __launch_bounds__(256)
void convert_kernel(const float* __restrict__ Qs, const float* __restrict__ Ks,
                    unsigned short* __restrict__ Qd, unsigned short* __restrict__ Kd) {
    const float* src = blockIdx.y ? Qs : Ks;
    unsigned short* dst = blockIdx.y ? Qd : Kd;
    const int base = blockIdx.x * (256 * 8) + threadIdx.x;   // u16x8 units
    const float4* s = (const float4*)src;
#pragma unroll
    for (int j = 0; j < 8; j++) {
        int i = base + j * 256;
        float4 a = s[2 * i];
        float4 b = s[2 * i + 1];
        u16x8 o;
        o[0] = f2bf(a.x); o[1] = f2bf(a.y); o[2] = f2bf(a.z); o[3] = f2bf(a.w);
        o[4] = f2bf(b.x); o[5] = f2bf(b.y); o[6] = f2bf(b.z); o[7] = f2bf(b.w);
        ((u16x8*)dst)[i] = o;
    }
}

// ---- P = exp((Q K^T)/sqrt(SEQ)) unnormalized, lower-triangle tiles only.
// 128x128 tile, BK=32, DOUBLE-BUFFERED LDS with fine-grained vmcnt waits:
// stage(k+1) issued before waiting on stage(k); raw s_barrier (no vmcnt(0)
// drain). Each wave issues exactly 4 global_load_lds per stage -> the wait
// for buffer k is s_waitcnt vmcnt(4) while k+1's loads stay in flight. ----
#define BM 128
#define BK 32
__global__ __launch_bounds__(256)
void logits_exp(const unsigned short* __restrict__ Qb, const unsigned short* __restrict__ Kb,
                float* __restrict__ out, float* __restrict__ partials) {
    const int tid = blockIdx.x;          // 0..135
    const int b = blockIdx.y;
    int tq = (int)((sqrtf(8.f * (float)tid + 1.f) - 1.f) * 0.5f);
    while ((tq + 1) * (tq + 2) / 2 <= tid) tq++;
    while (tq * (tq + 1) / 2 > tid) tq--;
    const int tk = tid - tq * (tq + 1) / 2;   // 0..tq  (tq <= 15)

    __shared__ __align__(16) unsigned short a_lds[2][BM * BK];  // 2 x 8 KiB
    __shared__ __align__(16) unsigned short b_lds[2][BM * BK];  // 2 x 8 KiB

    const int t = threadIdx.x;
    const int wave = t >> 6;
    const int lane = t & 63;
    const int l16 = lane & 15;
    const int quad = lane >> 4;
    const int wm = wave >> 1;      // 2x2 wave grid, each wave 64x64
    const int wn = wave & 1;

    const unsigned short* Qrow = Qb + ((size_t)b * SEQ + (size_t)tq * BM) * DIM;
    const unsigned short* Krow = Kb + ((size_t)b * SEQ + (size_t)tk * BM) * DIM;

    const int sr = lane >> 2;      // 0..15 row-within-instr
    const int kg = lane & 3;       // 0..3  k-group (8 bf16 each)

    f32x4 acc[4][4];
#pragma unroll
    for (int i = 0; i < 4; i++)
#pragma unroll
        for (int j = 0; j < 4; j++) acc[i][j] = (f32x4){0.f, 0.f, 0.f, 0.f};

    // stage one BK-slab into buffer `buf`; exactly 4 global_load_lds per wave
    auto stage = [&](int k0, int buf) {
#pragma unroll
        for (int j = 0; j < 2; j++) {
            int rg = (wave + 4 * j) * 16;           // row group base
            int row = rg + sr;
            load_lds16(Qrow + (size_t)row * DIM + k0 + kg * 8, &a_lds[buf][rg * BK]);
            load_lds16(Krow + (size_t)row * DIM + k0 + kg * 8, &b_lds[buf][rg * BK]);
        }
    };

    stage(0, 0);
    const int NITER = DIM / BK;    // 16
    for (int k = 0; k < NITER; k++) {
        const int buf = k & 1;
        if (k + 1 < NITER) {
            stage((k + 1) * BK, 1 - buf);
            // wait only for buffer `buf`'s 4 loads (4 newest = next slab's)
            __builtin_amdgcn_s_waitcnt(0x0F74);   // vmcnt(4), exp/lgkm unconstrained
            __builtin_amdgcn_s_barrier();
        } else {
            __syncthreads();                      // final slab: full drain
        }

        bf16x8 af[4], bf[4];
#pragma unroll
        for (int mi = 0; mi < 4; mi++)
            af[mi] = *(const bf16x8*)&a_lds[buf][(wm * 64 + mi * 16 + l16) * BK + quad * 8];
#pragma unroll
        for (int ni = 0; ni < 4; ni++)
            bf[ni] = *(const bf16x8*)&b_lds[buf][(wn * 64 + ni * 16 + l16) * BK + quad * 8];
#pragma unroll
        for (int mi = 0; mi < 4; mi++)
#pragma unroll
            for (int ni = 0; ni < 4; ni++)
                acc[mi][ni] = __builtin_amdgcn_mfma_f32_16x16x32_bf16(af[mi], bf[ni], acc[mi][ni], 0, 0, 0);

        if (k + 1 < NITER)
            __builtin_amdgcn_s_barrier();   // reuse guard before next overwrite of `buf`
    }

    const float scale = 0.02209708691207961f;  // 1/sqrt(2048)
    const bool diag = (tk == tq);
    float* outb = out + (size_t)b * SEQ * SEQ;
#pragma unroll
    for (int mi = 0; mi < 4; mi++) {
        const int rowb = tq * BM + wm * 64 + mi * 16 + quad * 4;
#pragma unroll
        for (int r = 0; r < 4; r++) {
            const int row = rowb + r;
            float psum = 0.f;
#pragma unroll
            for (int ni = 0; ni < 4; ni++) {
                const int col = tk * BM + wn * 64 + ni * 16 + l16;
                float e = __expf(acc[mi][ni][r] * scale);
                e = (!diag || col <= row) ? e : 0.f;
                psum += e;
                outb[(size_t)row * SEQ + col] = e;
            }
            psum += __shfl_xor(psum, 1);
            psum += __shfl_xor(psum, 2);
            psum += __shfl_xor(psum, 4);
            psum += __shfl_xor(psum, 8);
            if (l16 == 0)
                partials[((size_t)b * SEQ + row) * 32 + tk * 2 + wn] = psum;
        }
    }
}

// ---- per-row rescale + upper-triangle zero fill: 8 rows/block, one wave
// owns 2 rows; all 16 loads issued before any store (memory-level parallelism) ----
__global__ __launch_bounds__(256)
void rescale_kernel(float* __restrict__ out, const float* __restrict__ partials) {
    const int rowbase = blockIdx.x * 8;
    const int wave = threadIdx.x >> 6;
    const int lane = threadIdx.x & 63;
    const int g0 = rowbase + wave * 2;

    float inv[2];
    int n4v[2];
#pragma unroll
    for (int rr = 0; rr < 2; rr++) {
        const int grow = g0 + rr;
        const int q = grow & (SEQ - 1);
        const int tqt = q >> 7;
        const int nslots = (tqt + 1) * 2;        // <= 32
        n4v[rr] = (tqt + 1) * 32;
        float v = (lane < nslots) ? partials[(size_t)grow * 32 + lane] : 0.f;
        v += __shfl_xor(v, 1);
        v += __shfl_xor(v, 2);
        v += __shfl_xor(v, 4);
        v += __shfl_xor(v, 8);
        v += __shfl_xor(v, 16);
        inv[rr] = 1.0f / __shfl(v, 0);           // lane 0 holds the full sum
    }

    float4 vals[2][8];
#pragma unroll
    for (int rr = 0; rr < 2; rr++) {
        float4* row = (float4*)(out + (size_t)(g0 + rr) * SEQ);
#pragma unroll
        for (int j = 0; j < 8; j++) {
            const int i = lane + j * 64;
            if (i < n4v[rr]) vals[rr][j] = row[i];
        }
    }
#pragma unroll
    for (int rr = 0; rr < 2; rr++) {
        float4* row = (float4*)(out + (size_t)(g0 + rr) * SEQ);
        const float s = inv[rr];
#pragma unroll
        for (int j = 0; j < 8; j++) {
            const int i = lane + j * 64;
            float4 e;
            if (i < n4v[rr]) {
                e = vals[rr][j];
                e.x *= s; e.y *= s; e.z *= s; e.w *= s;
            } else {
                e = (float4){0.f, 0.f, 0.f, 0.f};
            }
            row[i] = e;
        }
    }
}

extern "C" void kernel_launch(void* const* d_in, const int* in_sizes, int n_in,
                              void* d_out, int out_size, void* d_ws, size_t ws_size,
                              hipStream_t stream) {
    // setup_inputs order: {"K": ..., "Q": ...}
    const float* Kp = (const float*)d_in[0];
    const float* Qp = (const float*)d_in[1];
    float* out = (float*)d_out;

    const size_t nElem = (size_t)B_SZ * SEQ * DIM;
    unsigned short* Qbf = (unsigned short*)d_ws;
    unsigned short* Kbf = Qbf + nElem;
    float* partials = (float*)(Kbf + nElem);          // [B*SEQ][32]

    convert_kernel<<<dim3(512, 2), dim3(256), 0, stream>>>(Qp, Kp, Qbf, Kbf);
    logits_exp<<<dim3(NTRI, B_SZ), dim3(256), 0, stream>>>(Qbf, Kbf, out, partials);
    rescale_kernel<<<dim3(B_SZ * SEQ / 8), dim3(256), 0, stream>>>(out, partials);
}